// Round 2
// baseline (16655.443 us; speedup 1.0000x reference)
//
#include <hip/hip_runtime.h>
#include <hip/hip_bf16.h>

// Bidirectional GRU encoder, B=64 T=1024 D=300 U=300.
// Round 2: dtype-adaptive (device-side f32-vs-bf16 detection), canonical
// weight conversion in ws, MFMA input GEMM + VALU f32 scan (128 wgs).

#define B_   64
#define T_   1024
#define D_   300
#define U_   300
#define NU   900      // 3U
#define KP   320      // padded K for input GEMM
#define NP   960      // padded N width of k_pad
#define XPW  912      // xp row stride (elements)
#define KL   32       // rk rows cached in LDS in scan (keep static LDS < 64 KB)

typedef short short8 __attribute__((ext_vector_type(8)));
typedef float floatx4 __attribute__((ext_vector_type(4)));

__device__ __forceinline__ float b2f_bits(unsigned short u) {
  union { unsigned int i; float f; } v; v.i = ((unsigned int)u) << 16; return v.f;
}
__device__ __forceinline__ float lo16(unsigned int w) {
  union { unsigned int i; float f; } v; v.i = w << 16; return v.f;
}
__device__ __forceinline__ float hi16(unsigned int w) {
  union { unsigned int i; float f; } v; v.i = w & 0xffff0000u; return v.f;
}
__device__ __forceinline__ unsigned short f2b(float f) {
  __hip_bfloat16 h = __float2bfloat16(f);  // RNE
  return *reinterpret_cast<unsigned short*>(&h);
}

// ---------------- K_detect: input dtype + mask dtype flags ----------------
// flags[0]: 1 if inputs (and hence all float tensors + output) are bf16, 0 if f32.
// flags[1]: mask layout: 0 = 4-byte (int32/f32), 1 = 1-byte, 2 = 2-byte (bf16/f16).
__global__ __launch_bounds__(64) void k_detect(const unsigned int* __restrict__ xw,
                                               const unsigned char* __restrict__ mb,
                                               int* __restrict__ flags) {
  __shared__ int red[64];
  int tid = threadIdx.x;
  int hits = 0;
  for (int i = tid; i < 2048; i += 64) {
    unsigned int lo = xw[i] & 0xFFFFu;
    int e = (int)((lo >> 7) & 0xFF);
    if (e >= 105 && e <= 135) hits++;   // plausible bf16 exponent for N(0,1)
  }
  red[tid] = hits;
  __syncthreads();
  if (tid == 0) {
    int s = 0;
    for (int i = 0; i < 64; ++i) s += red[i];
    flags[0] = (s >= 1024) ? 1 : 0;
    unsigned char b0 = mb[0], b1 = mb[1];  // mask[0][0] and next byte; both true bits
    flags[1] = (b1 == 0) ? 0 : ((b0 == 1 && b1 == 1) ? 1 : 2);
  }
}

// ---------------- K0: lengths from mask ----------------
__global__ __launch_bounds__(256) void k_lengths(const unsigned char* __restrict__ mraw,
                                                 const int* __restrict__ flags,
                                                 int* __restrict__ lens) {
  __shared__ int red[256];
  int b = blockIdx.x, tid = threadIdx.x;
  int mt = flags[1];
  int s = 0;
  if (mt == 0) {
    const int* m = (const int*)mraw;
    for (int t = tid; t < T_; t += 256) s += m[(size_t)b * T_ + t] ? 1 : 0;
  } else if (mt == 1) {
    for (int t = tid; t < T_; t += 256) s += mraw[(size_t)b * T_ + t] ? 1 : 0;
  } else {
    const unsigned short* m = (const unsigned short*)mraw;
    for (int t = tid; t < T_; t += 256) s += m[(size_t)b * T_ + t] ? 1 : 0;
  }
  red[tid] = s; __syncthreads();
  for (int off = 128; off > 0; off >>= 1) {
    if (tid < off) red[tid] += red[tid + off];
    __syncthreads();
  }
  if (tid == 0) lens[b] = red[0];
}

// ---------------- K1: pad x [65536,300] -> [65536,320] bf16 ----------------
__global__ __launch_bounds__(256) void k_xpad(const void* __restrict__ xraw,
                                              const int* __restrict__ flags,
                                              unsigned short* __restrict__ xp) {
  int id = blockIdx.x * 256 + threadIdx.x;   // 65536*40 threads, 8 elems each
  int row = id / 40, seg = id % 40;
  int kbase = seg * 8;
  int bf = flags[0];
  unsigned short v[8];
  if (bf) {
    const unsigned short* x = (const unsigned short*)xraw;
#pragma unroll
    for (int i = 0; i < 8; ++i) {
      int k = kbase + i;
      v[i] = (k < D_) ? x[(size_t)row * D_ + k] : (unsigned short)0;
    }
  } else {
    const float* x = (const float*)xraw;
#pragma unroll
    for (int i = 0; i < 8; ++i) {
      int k = kbase + i;
      v[i] = (k < D_) ? f2b(x[(size_t)row * D_ + k]) : (unsigned short)0;
    }
  }
  uint4 o;
  o.x = (unsigned)v[0] | ((unsigned)v[1] << 16);
  o.y = (unsigned)v[2] | ((unsigned)v[3] << 16);
  o.z = (unsigned)v[4] | ((unsigned)v[5] << 16);
  o.w = (unsigned)v[6] | ((unsigned)v[7] << 16);
  *(uint4*)(xp + (size_t)row * KP + kbase) = o;
}

// ---------------- K2: pad k_{fwd,bwd} -> [2][320,960] bf16 ----------------
__global__ __launch_bounds__(256) void k_wpad(const void* __restrict__ kf,
                                              const void* __restrict__ kb,
                                              const int* __restrict__ flags,
                                              unsigned short* __restrict__ kp) {
  int id = blockIdx.x * 256 + threadIdx.x;
  if (id >= 2 * KP * NP) return;
  int dir = id / (KP * NP);
  int r = id % (KP * NP);
  int k = r / NP, n = r % NP;
  int bf = flags[0];
  unsigned short v = 0;
  if (k < D_ && n < NU) {
    size_t si = (size_t)k * NU + n;
    if (bf) v = ((const unsigned short*)(dir ? kb : kf))[si];
    else    v = f2b(((const float*)(dir ? kb : kf))[si]);
  }
  kp[id] = v;
}

// ---------------- K_prep: canonical rk (bf16), biases (f32), wfc (bf16), bfc (f32) ----
__global__ __launch_bounds__(256) void k_prep(const void* __restrict__ rkf,
                                              const void* __restrict__ rkb,
                                              const void* __restrict__ bfw,
                                              const void* __restrict__ bbw,
                                              const void* __restrict__ wfc,
                                              const void* __restrict__ bfc,
                                              const int* __restrict__ flags,
                                              unsigned short* __restrict__ rkc,   // [2][300][900]
                                              float* __restrict__ biasc,          // [2][2][900]
                                              unsigned short* __restrict__ wfcc,  // [600][300]
                                              float* __restrict__ bfcc) {         // [300]
  int i = blockIdx.x * 256 + threadIdx.x;
  int bf = flags[0];
  if (i < 2 * D_ * NU) {
    int dir = i / (D_ * NU), r = i % (D_ * NU);
    const void* src = dir ? rkb : rkf;
    rkc[i] = bf ? ((const unsigned short*)src)[r] : f2b(((const float*)src)[r]);
  }
  if (i < 2 * 2 * NU) {
    int dir = i / (2 * NU), r = i % (2 * NU);
    const void* src = dir ? bbw : bfw;
    biasc[i] = bf ? b2f_bits(((const unsigned short*)src)[r]) : ((const float*)src)[r];
  }
  if (i < 2 * U_ * U_) {
    wfcc[i] = bf ? ((const unsigned short*)wfc)[i] : f2b(((const float*)wfc)[i]);
  }
  if (i < U_) {
    bfcc[i] = bf ? b2f_bits(((const unsigned short*)bfc)[i]) : ((const float*)bfc)[i];
  }
}

// ---------------- K3: xp = x @ k + b_in, MFMA 16x16x32 bf16 ----------------
// block tile 64x64, 4 waves, wave w owns rows [16w,16w+16), 4 N-tiles each.
template <bool XPF32>
__global__ __launch_bounds__(256) void k_gemm(const unsigned short* __restrict__ xpad,
                                              const unsigned short* __restrict__ kpad,  // [2][KP][NP]
                                              const float* __restrict__ biasc,          // [2][2][900]
                                              void* __restrict__ xp_out) {              // [2][65536][XPW]
  __shared__ __align__(16) unsigned short As[64 * 40];
  __shared__ __align__(16) unsigned short Bs[64 * 40];  // transposed: [n][k]
  int tid = threadIdx.x;
  int wave = tid >> 6, lane = tid & 63;
  int m0 = blockIdx.x * 64, n0 = blockIdx.y * 64;
  int dir = blockIdx.z;
  const unsigned short* Bsrc = kpad + (size_t)dir * KP * NP;
  const float* bin = biasc + (size_t)dir * 2 * NU;  // bias[0][:]

  floatx4 acc[4];
#pragma unroll
  for (int i = 0; i < 4; ++i) acc[i] = {0.f, 0.f, 0.f, 0.f};

  int arow = tid >> 2, aseg = tid & 3;
  int bk = tid & 31, bn8 = (tid >> 5) * 8;
  int fr = lane & 15, fq = lane >> 4;

  for (int kc = 0; kc < KP; kc += 32) {
    uint4 av = *(const uint4*)(xpad + (size_t)(m0 + arow) * KP + kc + aseg * 8);
    uint4 bv = *(const uint4*)(Bsrc + (size_t)(kc + bk) * NP + n0 + bn8);
    *(uint4*)(As + arow * 40 + aseg * 8) = av;
    unsigned short tmp[8];
    tmp[0] = bv.x & 0xffff; tmp[1] = bv.x >> 16;
    tmp[2] = bv.y & 0xffff; tmp[3] = bv.y >> 16;
    tmp[4] = bv.z & 0xffff; tmp[5] = bv.z >> 16;
    tmp[6] = bv.w & 0xffff; tmp[7] = bv.w >> 16;
#pragma unroll
    for (int i = 0; i < 8; ++i) Bs[(bn8 + i) * 40 + bk] = tmp[i];
    __syncthreads();
    short8 a = *(const short8*)(As + (wave * 16 + fr) * 40 + fq * 8);
#pragma unroll
    for (int nt = 0; nt < 4; ++nt) {
      short8 bfrag = *(const short8*)(Bs + (nt * 16 + fr) * 40 + fq * 8);
      acc[nt] = __builtin_amdgcn_mfma_f32_16x16x32_bf16(a, bfrag, acc[nt], 0, 0, 0);
    }
    __syncthreads();
  }
  // epilogue: C/D col=lane&15, row=quad*4+reg
#pragma unroll
  for (int nt = 0; nt < 4; ++nt) {
    int col = n0 + nt * 16 + fr;
    if (col >= XPW) continue;
    float bi = (col < NU) ? bin[col] : 0.f;
#pragma unroll
    for (int r = 0; r < 4; ++r) {
      int m = m0 + wave * 16 + fq * 4 + r;
      float v = acc[nt][r] + bi;
      size_t idx = ((size_t)dir * 65536 + m) * XPW + col;
      if (XPF32) ((float*)xp_out)[idx] = v;
      else ((unsigned short*)xp_out)[idx] = f2b(v);
    }
  }
}

// ---------------- K4: the GRU scan, one wg per (batch, dir) ----------------
template <bool XPF32>
__global__ __launch_bounds__(256) void k_scan(const unsigned short* __restrict__ rkc,  // [2][300][900]
                                              const float* __restrict__ biasc,         // [2][2][900]
                                              const void* __restrict__ xp_all,         // [2][65536][XPW]
                                              const int* __restrict__ lens,
                                              const int* __restrict__ flags,
                                              float* __restrict__ hfin,                // [2][64][304]
                                              void* __restrict__ outraw)               // [64][1024][600]
{
  __shared__ __align__(16) unsigned short wlds[KL * NU];  // 57,600 B
  __shared__ __align__(16) float h[304];
  __shared__ __align__(16) float rp[912];
  int tid = threadIdx.x;
  int b = blockIdx.x, dir = blockIdx.y;
  const unsigned short* rk = rkc + (size_t)dir * D_ * NU;
  const float* brec = biasc + (size_t)dir * 2 * NU + NU;  // bias[1][:]
  int len = lens[b];
  int obf = flags[0];
  unsigned short* out16 = (unsigned short*)outraw;
  float* out32 = (float*)outraw;

  {
    const unsigned int* src = (const unsigned int*)rk;
    unsigned int* dst = (unsigned int*)wlds;
    for (int i = tid; i < KL * NU / 2; i += 256) dst[i] = src[i];
  }
  for (int i = tid; i < 304; i += 256) h[i] = 0.f;
  __syncthreads();

  int c = tid;       // column group: owns cols 4c..4c+3 (c < 225)
  int j = 4 * c;

  for (int s = 0; s < T_; ++s) {
    int t = dir ? (T_ - 1 - s) : s;
    size_t row = (size_t)b * T_ + t;
    if (t < len) {
      if (c < 225) {
        float a0 = brec[j], a1 = brec[j + 1], a2 = brec[j + 2], a3 = brec[j + 3];
        for (int k0 = 0; k0 < KL; k0 += 4) {
          float4 h4 = *(const float4*)(h + k0);
#pragma unroll
          for (int i = 0; i < 4; ++i) {
            uint2 w = *(const uint2*)(wlds + (k0 + i) * NU + j);
            float hk = ((const float*)&h4)[i];
            a0 = fmaf(lo16(w.x), hk, a0);
            a1 = fmaf(hi16(w.x), hk, a1);
            a2 = fmaf(lo16(w.y), hk, a2);
            a3 = fmaf(hi16(w.y), hk, a3);
          }
        }
        for (int k0 = KL; k0 < D_; k0 += 4) {
          float4 h4 = *(const float4*)(h + k0);
#pragma unroll
          for (int i = 0; i < 4; ++i) {
            uint2 w = *(const uint2*)(rk + (size_t)(k0 + i) * NU + j);
            float hk = ((const float*)&h4)[i];
            a0 = fmaf(lo16(w.x), hk, a0);
            a1 = fmaf(hi16(w.x), hk, a1);
            a2 = fmaf(lo16(w.y), hk, a2);
            a3 = fmaf(hi16(w.y), hk, a3);
          }
        }
        rp[j] = a0; rp[j + 1] = a1; rp[j + 2] = a2; rp[j + 3] = a3;
      }
      __syncthreads();
      for (int u = tid; u < U_; u += 256) {
        float xz, xr, xh;
        if (XPF32) {
          const float* xrow = (const float*)xp_all + ((size_t)dir * 65536 + row) * XPW;
          xz = xrow[u]; xr = xrow[u + U_]; xh = xrow[u + 2 * U_];
        } else {
          const unsigned short* xrow =
              (const unsigned short*)xp_all + ((size_t)dir * 65536 + row) * XPW;
          xz = b2f_bits(xrow[u]); xr = b2f_bits(xrow[u + U_]); xh = b2f_bits(xrow[u + 2 * U_]);
        }
        float z = 1.f / (1.f + __expf(-(xz + rp[u])));
        float r = 1.f / (1.f + __expf(-(xr + rp[u + U_])));
        float hh = tanhf(xh + r * rp[u + 2 * U_]);
        float hold = h[u];
        float hn = z * hold + (1.f - z) * hh;
        h[u] = hn;
        size_t oi = row * 600 + (size_t)dir * U_ + u;
        if (obf) out16[oi] = f2b(hn); else out32[oi] = hn;
      }
      __syncthreads();
    } else {
      for (int u = tid; u < U_; u += 256) {
        size_t oi = row * 600 + (size_t)dir * U_ + u;
        if (obf) out16[oi] = 0; else out32[oi] = 0.f;
      }
    }
  }
  for (int u = tid; u < U_; u += 256) hfin[((size_t)dir * B_ + b) * 304 + u] = h[u];
}

// ---------------- K5: state = relu(concat(h_f,h_b) @ w_fc + b_fc) ----------------
__global__ __launch_bounds__(320) void k_state(const float* __restrict__ hfin,
                                               const unsigned short* __restrict__ wfcc,  // [600][300]
                                               const float* __restrict__ bfcc,           // [300]
                                               const int* __restrict__ flags,
                                               void* __restrict__ outraw) {  // at element offset B*T*600
  int b = blockIdx.x, u = threadIdx.x;
  if (u >= U_) return;
  int obf = flags[0];
  float acc = bfcc[u];
  const float* hf = hfin + (size_t)b * 304;
  const float* hb = hfin + ((size_t)B_ + b) * 304;
  for (int k = 0; k < U_; ++k) acc = fmaf(hf[k], b2f_bits(wfcc[(size_t)k * U_ + u]), acc);
  for (int k = 0; k < U_; ++k) acc = fmaf(hb[k], b2f_bits(wfcc[(size_t)(U_ + k) * U_ + u]), acc);
  float v = fmaxf(acc, 0.f);
  size_t oi = (size_t)B_ * T_ * 600 + (size_t)b * U_ + u;
  if (obf) ((unsigned short*)outraw)[oi] = f2b(v);
  else     ((float*)outraw)[oi] = v;
}

extern "C" void kernel_launch(void* const* d_in, const int* in_sizes, int n_in,
                              void* d_out, int out_size, void* d_ws, size_t ws_size,
                              hipStream_t stream) {
  const void* x    = d_in[0];
  const void* mask = d_in[1];
  const void* kf   = d_in[2];
  const void* rkf  = d_in[3];
  const void* bfw  = d_in[4];
  const void* kb   = d_in[5];
  const void* rkb  = d_in[6];
  const void* bbw  = d_in[7];
  const void* wfc  = d_in[8];
  const void* bfc  = d_in[9];

  char* ws = (char*)d_ws;
  size_t off = 0;
  auto alloc = [&](size_t bytes) { void* p = ws + off; off += (bytes + 255) & ~(size_t)255; return p; };
  int* flags            = (int*)alloc(256);
  int* lens             = (int*)alloc(256);
  unsigned short* xpad  = (unsigned short*)alloc((size_t)65536 * KP * 2);     // 41.94 MB
  unsigned short* kpad  = (unsigned short*)alloc((size_t)2 * KP * NP * 2);    // 1.23 MB
  unsigned short* rkc   = (unsigned short*)alloc((size_t)2 * D_ * NU * 2);    // 1.08 MB
  float* biasc          = (float*)alloc((size_t)2 * 2 * NU * 4);
  unsigned short* wfcc  = (unsigned short*)alloc((size_t)2 * U_ * U_ * 2);
  float* bfcc           = (float*)alloc((size_t)U_ * 4);
  float* hfin           = (float*)alloc((size_t)2 * B_ * 304 * 4);
  void* xp = (void*)(ws + off);
  size_t need_f32 = off + (size_t)2 * 65536 * XPW * 4;  // ~523 MB total
  bool xpf32 = ws_size >= need_f32;

  k_detect<<<dim3(1), dim3(64), 0, stream>>>((const unsigned int*)x, (const unsigned char*)mask, flags);
  k_lengths<<<dim3(B_), dim3(256), 0, stream>>>((const unsigned char*)mask, flags, lens);
  k_xpad<<<dim3(65536 * 40 / 256), dim3(256), 0, stream>>>(x, flags, xpad);
  k_wpad<<<dim3((2 * KP * NP + 255) / 256), dim3(256), 0, stream>>>(kf, kb, flags, kpad);
  k_prep<<<dim3((2 * D_ * NU + 255) / 256), dim3(256), 0, stream>>>(rkf, rkb, bfw, bbw, wfc, bfc,
                                                                    flags, rkc, biasc, wfcc, bfcc);
  if (xpf32) {
    k_gemm<true><<<dim3(1024, 15, 2), dim3(256), 0, stream>>>(xpad, kpad, biasc, xp);
    k_scan<true><<<dim3(B_, 2), dim3(256), 0, stream>>>(rkc, biasc, xp, lens, flags, hfin, d_out);
  } else {
    k_gemm<false><<<dim3(1024, 15, 2), dim3(256), 0, stream>>>(xpad, kpad, biasc, xp);
    k_scan<false><<<dim3(B_, 2), dim3(256), 0, stream>>>(rkc, biasc, xp, lens, flags, hfin, d_out);
  }
  k_state<<<dim3(B_), dim3(320), 0, stream>>>(hfin, wfcc, bfcc, flags, d_out);
}

// Round 4
// 14019.070 us; speedup vs baseline: 1.1881x; 1.1881x over previous
//
#include <hip/hip_runtime.h>
#include <hip/hip_bf16.h>

// Bidirectional GRU encoder, B=64 T=1024 D=300 U=300.
// Round 4: R3 design with the deadlock fixed (ctrs[64] for dir=1 was never
// zeroed -> poisoned counter -> spin-wait never satisfied -> GPU hang).
// Cooperative scan: 15 wgs/direction, register-resident B-fragments,
// bf16 hi/lo h double-buffer, one agent-scope barrier per step.

#define B_   64
#define T_   1024
#define D_   300
#define U_   300
#define NU   900      // 3U
#define KP   320      // padded K for input GEMM
#define NP   960      // padded N width of k_pad
#define XPW  912      // xp row stride (elements)
#define NW   15       // workgroups per direction in scan
#define W_   20       // u-columns per scan wg
#define HS   320      // h buffer row stride (elements, zero-padded 300..319)
#define KB_  10       // K blocks of 32 (320/32)

typedef short short8 __attribute__((ext_vector_type(8)));
typedef float floatx4 __attribute__((ext_vector_type(4)));

__device__ __forceinline__ float b2f_bits(unsigned short u) {
  union { unsigned int i; float f; } v; v.i = ((unsigned int)u) << 16; return v.f;
}
__device__ __forceinline__ unsigned short f2b(float f) {
  __hip_bfloat16 h = __float2bfloat16(f);  // RNE
  return *reinterpret_cast<unsigned short*>(&h);
}

// ---------------- K_detect: input dtype + mask dtype flags ----------------
__global__ __launch_bounds__(64) void k_detect(const unsigned int* __restrict__ xw,
                                               const unsigned char* __restrict__ mb,
                                               int* __restrict__ flags) {
  __shared__ int red[64];
  int tid = threadIdx.x;
  int hits = 0;
  for (int i = tid; i < 2048; i += 64) {
    unsigned int lo = xw[i] & 0xFFFFu;
    int e = (int)((lo >> 7) & 0xFF);
    if (e >= 105 && e <= 135) hits++;   // plausible bf16 exponent for N(0,1)
  }
  red[tid] = hits;
  __syncthreads();
  if (tid == 0) {
    int s = 0;
    for (int i = 0; i < 64; ++i) s += red[i];
    flags[0] = (s >= 1024) ? 1 : 0;
    unsigned char b0 = mb[0], b1 = mb[1];
    flags[1] = (b1 == 0) ? 0 : ((b0 == 1 && b1 == 1) ? 1 : 2);
  }
}

// ---------------- K0: lengths from mask ----------------
__global__ __launch_bounds__(256) void k_lengths(const unsigned char* __restrict__ mraw,
                                                 const int* __restrict__ flags,
                                                 int* __restrict__ lens) {
  __shared__ int red[256];
  int b = blockIdx.x, tid = threadIdx.x;
  int mt = flags[1];
  int s = 0;
  if (mt == 0) {
    const int* m = (const int*)mraw;
    for (int t = tid; t < T_; t += 256) s += m[(size_t)b * T_ + t] ? 1 : 0;
  } else if (mt == 1) {
    for (int t = tid; t < T_; t += 256) s += mraw[(size_t)b * T_ + t] ? 1 : 0;
  } else {
    const unsigned short* m = (const unsigned short*)mraw;
    for (int t = tid; t < T_; t += 256) s += m[(size_t)b * T_ + t] ? 1 : 0;
  }
  red[tid] = s; __syncthreads();
  for (int off = 128; off > 0; off >>= 1) {
    if (tid < off) red[tid] += red[tid + off];
    __syncthreads();
  }
  if (tid == 0) lens[b] = red[0];
}

// ---------------- K_init: zero h double-buffers + ALL barrier counters ----------------
__global__ __launch_bounds__(256) void k_init(unsigned short* __restrict__ hHi,
                                              unsigned short* __restrict__ hLo,
                                              int* __restrict__ ctrs) {
  int i = blockIdx.x * 256 + threadIdx.x;   // over uints
  const int nu = 2 * 2 * B_ * HS / 2;       // uints per array
  unsigned int* a = (unsigned int*)hHi;
  unsigned int* b = (unsigned int*)hLo;
  if (i < nu) { a[i] = 0u; b[i] = 0u; }
  if (i < 128) ctrs[i] = 0;   // FIX: dir=1 uses ctrs[64]; zero the whole 512B region
}

// ---------------- K1: pad x -> [65536,320] bf16 ----------------
__global__ __launch_bounds__(256) void k_xpad(const void* __restrict__ xraw,
                                              const int* __restrict__ flags,
                                              unsigned short* __restrict__ xp) {
  int id = blockIdx.x * 256 + threadIdx.x;
  int row = id / 40, seg = id % 40;
  int kbase = seg * 8;
  int bf = flags[0];
  unsigned short v[8];
  if (bf) {
    const unsigned short* x = (const unsigned short*)xraw;
#pragma unroll
    for (int i = 0; i < 8; ++i) {
      int k = kbase + i;
      v[i] = (k < D_) ? x[(size_t)row * D_ + k] : (unsigned short)0;
    }
  } else {
    const float* x = (const float*)xraw;
#pragma unroll
    for (int i = 0; i < 8; ++i) {
      int k = kbase + i;
      v[i] = (k < D_) ? f2b(x[(size_t)row * D_ + k]) : (unsigned short)0;
    }
  }
  uint4 o;
  o.x = (unsigned)v[0] | ((unsigned)v[1] << 16);
  o.y = (unsigned)v[2] | ((unsigned)v[3] << 16);
  o.z = (unsigned)v[4] | ((unsigned)v[5] << 16);
  o.w = (unsigned)v[6] | ((unsigned)v[7] << 16);
  *(uint4*)(xp + (size_t)row * KP + kbase) = o;
}

// ---------------- K2: pad k_{fwd,bwd} -> [2][320,960] bf16 ----------------
__global__ __launch_bounds__(256) void k_wpad(const void* __restrict__ kf,
                                              const void* __restrict__ kb,
                                              const int* __restrict__ flags,
                                              unsigned short* __restrict__ kp) {
  int id = blockIdx.x * 256 + threadIdx.x;
  if (id >= 2 * KP * NP) return;
  int dir = id / (KP * NP);
  int r = id % (KP * NP);
  int k = r / NP, n = r % NP;
  int bf = flags[0];
  unsigned short v = 0;
  if (k < D_ && n < NU) {
    size_t si = (size_t)k * NU + n;
    if (bf) v = ((const unsigned short*)(dir ? kb : kf))[si];
    else    v = f2b(((const float*)(dir ? kb : kf))[si]);
  }
  kp[id] = v;
}

// ---------------- K_prep: canonical rk (bf16), biases (f32), wfc, bfc ----------------
__global__ __launch_bounds__(256) void k_prep(const void* __restrict__ rkf,
                                              const void* __restrict__ rkb,
                                              const void* __restrict__ bfw,
                                              const void* __restrict__ bbw,
                                              const void* __restrict__ wfc,
                                              const void* __restrict__ bfc,
                                              const int* __restrict__ flags,
                                              unsigned short* __restrict__ rkc,   // [2][300][900]
                                              float* __restrict__ biasc,          // [2][2][900]
                                              unsigned short* __restrict__ wfcc,  // [600][300]
                                              float* __restrict__ bfcc) {         // [300]
  int i = blockIdx.x * 256 + threadIdx.x;
  int bf = flags[0];
  if (i < 2 * D_ * NU) {
    int dir = i / (D_ * NU), r = i % (D_ * NU);
    const void* src = dir ? rkb : rkf;
    rkc[i] = bf ? ((const unsigned short*)src)[r] : f2b(((const float*)src)[r]);
  }
  if (i < 2 * 2 * NU) {
    int dir = i / (2 * NU), r = i % (2 * NU);
    const void* src = dir ? bbw : bfw;
    biasc[i] = bf ? b2f_bits(((const unsigned short*)src)[r]) : ((const float*)src)[r];
  }
  if (i < 2 * U_ * U_) {
    wfcc[i] = bf ? ((const unsigned short*)wfc)[i] : f2b(((const float*)wfc)[i]);
  }
  if (i < U_) {
    bfcc[i] = bf ? b2f_bits(((const unsigned short*)bfc)[i]) : ((const float*)bfc)[i];
  }
}

// ---------------- K_bpack: rk -> per-wg MFMA B-fragment layout ----------------
// bpack[((dir*NW+wg)*40 + kb*4+nt)*512 + lane*8 + j] =
//   rk[k = kb*32 + (lane>>4)*8 + j][col(n = nt*16 + (lane&15))], 0 if pad.
__global__ __launch_bounds__(256) void k_bpack(const unsigned short* __restrict__ rkc,
                                               unsigned short* __restrict__ bpack) {
  int idx = blockIdx.x * 256 + threadIdx.x;
  const int total = 2 * NW * 40 * 512;
  if (idx >= total) return;
  int rem = idx;
  int j = rem & 7; rem >>= 3;
  int lane = rem & 63; rem >>= 6;
  int f = rem % 40; rem /= 40;
  int wg = rem % NW;
  int dir = rem / NW;
  int kb = f >> 2, nt = f & 3;
  int l15 = lane & 15, quad = lane >> 4;
  int k = kb * 32 + quad * 8 + j;
  int n = nt * 16 + l15;
  unsigned short v = 0;
  if (n < 3 * W_ && k < D_) {
    int g = n / W_, i = n % W_;
    int col = g * U_ + wg * W_ + i;
    v = rkc[(size_t)dir * D_ * NU + (size_t)k * NU + col];
  }
  bpack[idx] = v;
}

// ---------------- K3: xp = x @ k + b_in, MFMA 16x16x32 bf16 ----------------
template <bool XPF32>
__global__ __launch_bounds__(256) void k_gemm(const unsigned short* __restrict__ xpad,
                                              const unsigned short* __restrict__ kpad,
                                              const float* __restrict__ biasc,
                                              void* __restrict__ xp_out) {
  __shared__ __align__(16) unsigned short As[64 * 40];
  __shared__ __align__(16) unsigned short Bs[64 * 40];  // transposed: [n][k]
  int tid = threadIdx.x;
  int wave = tid >> 6, lane = tid & 63;
  int m0 = blockIdx.x * 64, n0 = blockIdx.y * 64;
  int dir = blockIdx.z;
  const unsigned short* Bsrc = kpad + (size_t)dir * KP * NP;
  const float* bin = biasc + (size_t)dir * 2 * NU;

  floatx4 acc[4];
#pragma unroll
  for (int i = 0; i < 4; ++i) acc[i] = {0.f, 0.f, 0.f, 0.f};

  int arow = tid >> 2, aseg = tid & 3;
  int bk = tid & 31, bn8 = (tid >> 5) * 8;
  int fr = lane & 15, fq = lane >> 4;

  for (int kc = 0; kc < KP; kc += 32) {
    uint4 av = *(const uint4*)(xpad + (size_t)(m0 + arow) * KP + kc + aseg * 8);
    uint4 bv = *(const uint4*)(Bsrc + (size_t)(kc + bk) * NP + n0 + bn8);
    *(uint4*)(As + arow * 40 + aseg * 8) = av;
    unsigned short tmp[8];
    tmp[0] = bv.x & 0xffff; tmp[1] = bv.x >> 16;
    tmp[2] = bv.y & 0xffff; tmp[3] = bv.y >> 16;
    tmp[4] = bv.z & 0xffff; tmp[5] = bv.z >> 16;
    tmp[6] = bv.w & 0xffff; tmp[7] = bv.w >> 16;
#pragma unroll
    for (int i = 0; i < 8; ++i) Bs[(bn8 + i) * 40 + bk] = tmp[i];
    __syncthreads();
    short8 a = *(const short8*)(As + (wave * 16 + fr) * 40 + fq * 8);
#pragma unroll
    for (int nt = 0; nt < 4; ++nt) {
      short8 bfrag = *(const short8*)(Bs + (nt * 16 + fr) * 40 + fq * 8);
      acc[nt] = __builtin_amdgcn_mfma_f32_16x16x32_bf16(a, bfrag, acc[nt], 0, 0, 0);
    }
    __syncthreads();
  }
#pragma unroll
  for (int nt = 0; nt < 4; ++nt) {
    int col = n0 + nt * 16 + fr;
    if (col >= XPW) continue;
    float bi = (col < NU) ? bin[col] : 0.f;
#pragma unroll
    for (int r = 0; r < 4; ++r) {
      int m = m0 + wave * 16 + fq * 4 + r;
      float v = acc[nt][r] + bi;
      size_t idx = ((size_t)dir * 65536 + m) * XPW + col;
      if (XPF32) ((float*)xp_out)[idx] = v;
      else ((unsigned short*)xp_out)[idx] = f2b(v);
    }
  }
}

// ---------------- K4: cooperative GRU scan ----------------
// grid (NW, 2). Wave w computes batch rows 16w..16w+15 of rp = h@rk_slice.
// h: global double buffer, bf16 hi+lo (par = s&1). One barrier per step.
template <bool XPF32>
__global__ __launch_bounds__(256, 1) void k_scan(const unsigned short* __restrict__ bpack,
                                                 const float* __restrict__ biasc,
                                                 const void* __restrict__ xp_all,
                                                 const int* __restrict__ lens,
                                                 const int* __restrict__ flags,
                                                 unsigned short* __restrict__ hHi,  // [2][2][64*HS]
                                                 unsigned short* __restrict__ hLo,
                                                 float* __restrict__ hfin,          // [2][64][304]
                                                 int* __restrict__ ctrs,
                                                 void* __restrict__ outraw) {
  __shared__ __align__(16) float rp[64 * 68];
  int tid = threadIdx.x;
  int wg = blockIdx.x, dir = blockIdx.y;
  int wave = tid >> 6, lane = tid & 63;
  int l15 = lane & 15, quad = lane >> 4;
  int obf = flags[0];
  unsigned short* out16 = (unsigned short*)outraw;
  float* out32 = (float*)outraw;

  // register-resident B fragments (constant across all 1024 steps)
  short8 breg[KB_][4];
  {
    const unsigned short* bp = bpack + ((size_t)(dir * NW + wg) * 40) * 512 + lane * 8;
#pragma unroll
    for (int kb = 0; kb < KB_; ++kb)
#pragma unroll
      for (int nt = 0; nt < 4; ++nt)
        breg[kb][nt] = *(const short8*)(bp + (size_t)(kb * 4 + nt) * 512);
  }

  // epilogue ownership: thread -> (batch eb, cols u0+ei .. u0+ei+4)
  int eb = tid >> 2;            // 0..63
  int ei = (tid & 3) * 5;       // 0,5,10,15
  int u0 = wg * W_;
  int mylen = lens[eb];
  const float* brec = biasc + (size_t)dir * 2 * NU + NU;
  float bz[5], brr[5], bh[5], hold[5];
#pragma unroll
  for (int q = 0; q < 5; ++q) {
    int u = u0 + ei + q;
    bz[q] = brec[u]; brr[q] = brec[U_ + u]; bh[q] = brec[2 * U_ + u];
    hold[q] = 0.f;
  }

  int ctr_target = 0;
  int* myctr = ctrs + dir * 64;  // 256-B separated counters

#pragma unroll 1
  for (int s = 0; s < T_; ++s) {
    int t = dir ? (T_ - 1 - s) : s;
    int par = s & 1;
    const unsigned short* hh = hHi + (size_t)(par * 2 + dir) * (B_ * HS);
    const unsigned short* hl = hLo + (size_t)(par * 2 + dir) * (B_ * HS);

    // issue xp loads early (hidden behind MFMA phase)
    float xz[5], xr[5], xh[5];
    {
      size_t rowoff = ((size_t)dir * 65536 + (size_t)eb * T_ + t) * XPW;
      if (XPF32) {
        const float* xrow = (const float*)xp_all + rowoff;
#pragma unroll
        for (int q = 0; q < 5; ++q) {
          int u = u0 + ei + q;
          xz[q] = xrow[u]; xr[q] = xrow[U_ + u]; xh[q] = xrow[2 * U_ + u];
        }
      } else {
        const unsigned short* xrow = (const unsigned short*)xp_all + rowoff;
#pragma unroll
        for (int q = 0; q < 5; ++q) {
          int u = u0 + ei + q;
          xz[q] = b2f_bits(xrow[u]); xr[q] = b2f_bits(xrow[U_ + u]); xh[q] = b2f_bits(xrow[2 * U_ + u]);
        }
      }
    }

    // rp = h_hi @ Wslice + h_lo @ Wslice  (A from global, B in regs)
    floatx4 acc[4];
#pragma unroll
    for (int i = 0; i < 4; ++i) acc[i] = {0.f, 0.f, 0.f, 0.f};
    {
      const unsigned short* ah_base = hh + (size_t)(wave * 16 + l15) * HS + quad * 8;
      const unsigned short* al_base = hl + (size_t)(wave * 16 + l15) * HS + quad * 8;
#pragma unroll
      for (int kb = 0; kb < KB_; ++kb) {
        short8 ah = *(const short8*)(ah_base + kb * 32);
        short8 al = *(const short8*)(al_base + kb * 32);
#pragma unroll
        for (int nt = 0; nt < 4; ++nt)
          acc[nt] = __builtin_amdgcn_mfma_f32_16x16x32_bf16(ah, breg[kb][nt], acc[nt], 0, 0, 0);
#pragma unroll
        for (int nt = 0; nt < 4; ++nt)
          acc[nt] = __builtin_amdgcn_mfma_f32_16x16x32_bf16(al, breg[kb][nt], acc[nt], 0, 0, 0);
      }
    }
    // C layout: row = wave*16 + quad*4 + r (batch), col = nt*16 + l15 (gate col)
#pragma unroll
    for (int nt = 0; nt < 4; ++nt)
#pragma unroll
      for (int r = 0; r < 4; ++r)
        rp[(wave * 16 + quad * 4 + r) * 68 + nt * 16 + l15] = acc[nt][r];
    __syncthreads();

    // epilogue: gates + h update for owned (eb, u0+ei..+4)
    bool m = (t < mylen);
    unsigned short* nhh = hHi + (size_t)(((s + 1) & 1) * 2 + dir) * (B_ * HS);
    unsigned short* nhl = hLo + (size_t)(((s + 1) & 1) * 2 + dir) * (B_ * HS);
    size_t obase = ((size_t)eb * T_ + t) * 600 + (size_t)dir * U_ + u0 + ei;
#pragma unroll
    for (int q = 0; q < 5; ++q) {
      int i = ei + q;
      float rz = rp[eb * 68 + i];
      float rr = rp[eb * 68 + W_ + i];
      float rh = rp[eb * 68 + 2 * W_ + i];
      float z = 1.f / (1.f + __expf(-(xz[q] + rz + bz[q])));
      float r = 1.f / (1.f + __expf(-(xr[q] + rr + brr[q])));
      float hhat = tanhf(xh[q] + r * (rh + bh[q]));
      float hn = z * hold[q] + (1.f - z) * hhat;
      float hw = m ? hn : hold[q];
      hold[q] = hw;
      float y = m ? hn : 0.f;
      if (obf) out16[obase + q] = f2b(y); else out32[obase + q] = y;
      unsigned short hib = f2b(hw);
      float lo = hw - b2f_bits(hib);
      nhh[eb * HS + u0 + i] = hib;
      nhl[eb * HS + u0 + i] = f2b(lo);
    }

    // device barrier for this direction (release h writes, acquire for next read)
    __threadfence();
    __syncthreads();
    ctr_target += NW;
    if (tid == 0) {
      __hip_atomic_fetch_add(myctr, 1, __ATOMIC_ACQ_REL, __HIP_MEMORY_SCOPE_AGENT);
      while (__hip_atomic_load(myctr, __ATOMIC_ACQUIRE, __HIP_MEMORY_SCOPE_AGENT) < ctr_target)
        __builtin_amdgcn_s_sleep(1);
    }
    __syncthreads();
    __threadfence();
  }

#pragma unroll
  for (int q = 0; q < 5; ++q)
    hfin[((size_t)dir * B_ + eb) * 304 + u0 + ei + q] = hold[q];
}

// ---------------- K5: state = relu(concat(h_f,h_b) @ w_fc + b_fc) ----------------
__global__ __launch_bounds__(320) void k_state(const float* __restrict__ hfin,
                                               const unsigned short* __restrict__ wfcc,
                                               const float* __restrict__ bfcc,
                                               const int* __restrict__ flags,
                                               void* __restrict__ outraw) {
  int b = blockIdx.x, u = threadIdx.x;
  if (u >= U_) return;
  int obf = flags[0];
  float acc = bfcc[u];
  const float* hf = hfin + (size_t)b * 304;
  const float* hb = hfin + ((size_t)B_ + b) * 304;
  for (int k = 0; k < U_; ++k) acc = fmaf(hf[k], b2f_bits(wfcc[(size_t)k * U_ + u]), acc);
  for (int k = 0; k < U_; ++k) acc = fmaf(hb[k], b2f_bits(wfcc[(size_t)(U_ + k) * U_ + u]), acc);
  float v = fmaxf(acc, 0.f);
  size_t oi = (size_t)B_ * T_ * 600 + (size_t)b * U_ + u;
  if (obf) ((unsigned short*)outraw)[oi] = f2b(v);
  else     ((float*)outraw)[oi] = v;
}

extern "C" void kernel_launch(void* const* d_in, const int* in_sizes, int n_in,
                              void* d_out, int out_size, void* d_ws, size_t ws_size,
                              hipStream_t stream) {
  const void* x    = d_in[0];
  const void* mask = d_in[1];
  const void* kf   = d_in[2];
  const void* rkf  = d_in[3];
  const void* bfw  = d_in[4];
  const void* kb   = d_in[5];
  const void* rkb  = d_in[6];
  const void* bbw  = d_in[7];
  const void* wfc  = d_in[8];
  const void* bfc  = d_in[9];

  char* ws = (char*)d_ws;
  size_t off = 0;
  auto alloc = [&](size_t bytes) { void* p = ws + off; off += (bytes + 255) & ~(size_t)255; return p; };
  int* flags            = (int*)alloc(256);
  int* lens             = (int*)alloc(256);
  int* ctrs             = (int*)alloc(512);
  unsigned short* xpad  = (unsigned short*)alloc((size_t)65536 * KP * 2);
  unsigned short* kpad  = (unsigned short*)alloc((size_t)2 * KP * NP * 2);
  unsigned short* rkc   = (unsigned short*)alloc((size_t)2 * D_ * NU * 2);
  unsigned short* bpack = (unsigned short*)alloc((size_t)2 * NW * 40 * 512 * 2);
  float* biasc          = (float*)alloc((size_t)2 * 2 * NU * 4);
  unsigned short* wfcc  = (unsigned short*)alloc((size_t)2 * U_ * U_ * 2);
  float* bfcc           = (float*)alloc((size_t)U_ * 4);
  float* hfin           = (float*)alloc((size_t)2 * B_ * 304 * 4);
  unsigned short* hHi   = (unsigned short*)alloc((size_t)2 * 2 * B_ * HS * 2);
  unsigned short* hLo   = (unsigned short*)alloc((size_t)2 * 2 * B_ * HS * 2);
  void* xp = (void*)(ws + off);
  size_t need_f32 = off + (size_t)2 * 65536 * XPW * 4;
  bool xpf32 = ws_size >= need_f32;

  k_detect<<<dim3(1), dim3(64), 0, stream>>>((const unsigned int*)x, (const unsigned char*)mask, flags);
  k_lengths<<<dim3(B_), dim3(256), 0, stream>>>((const unsigned char*)mask, flags, lens);
  k_init<<<dim3((2 * 2 * B_ * HS / 2 + 255) / 256), dim3(256), 0, stream>>>(hHi, hLo, ctrs);
  k_xpad<<<dim3(65536 * 40 / 256), dim3(256), 0, stream>>>(x, flags, xpad);
  k_wpad<<<dim3((2 * KP * NP + 255) / 256), dim3(256), 0, stream>>>(kf, kb, flags, kpad);
  k_prep<<<dim3((2 * D_ * NU + 255) / 256), dim3(256), 0, stream>>>(rkf, rkb, bfw, bbw, wfc, bfc,
                                                                    flags, rkc, biasc, wfcc, bfcc);
  k_bpack<<<dim3((2 * NW * 40 * 512 + 255) / 256), dim3(256), 0, stream>>>(rkc, bpack);
  if (xpf32) {
    k_gemm<true><<<dim3(1024, 15, 2), dim3(256), 0, stream>>>(xpad, kpad, biasc, xp);
    k_scan<true><<<dim3(NW, 2), dim3(256), 0, stream>>>(bpack, biasc, xp, lens, flags,
                                                        hHi, hLo, hfin, ctrs, d_out);
  } else {
    k_gemm<false><<<dim3(1024, 15, 2), dim3(256), 0, stream>>>(xpad, kpad, biasc, xp);
    k_scan<false><<<dim3(NW, 2), dim3(256), 0, stream>>>(bpack, biasc, xp, lens, flags,
                                                         hHi, hLo, hfin, ctrs, d_out);
  }
  k_state<<<dim3(B_), dim3(320), 0, stream>>>(hfin, wfcc, bfcc, flags, d_out);
}